// Round 4
// baseline (279.985 us; speedup 1.0000x reference)
//
#include <hip/hip_runtime.h>
#include <hip/hip_bf16.h>

// LocalAttn: B=8 S=1024 E=512 H=16 D=32, rel-pos bias, NO causal mask.
// f32 inputs / f32 output. Internals bf16 for MFMA.
// R4 = R3 with the __hip_bfloat162 bit_cast compile fix (manual pack).
// R3: conflict-free LDS strides (qr stride 19 odd -> skew gather <=2-way;
// was 8-way at stride 20), P packed as u32 (j,j+16) pairs + k-permuted PV
// MFMA fed by an interleaved V layout written by proj.

typedef short bf16x8 __attribute__((ext_vector_type(8)));   // 8 bf16 (4 VGPRs)
typedef float f32x4 __attribute__((ext_vector_type(4)));
typedef unsigned short u16x4 __attribute__((ext_vector_type(4)));
typedef unsigned int u32x4 __attribute__((ext_vector_type(4)));

#if __has_builtin(__builtin_amdgcn_exp2f)
#define EXP2F(x) __builtin_amdgcn_exp2f(x)
#else
#define EXP2F(x) exp2f(x)
#endif

constexpr int Bb = 8, Ss = 1024, Ee = 512, Hh = 16, Dd = 32;
// log2(e)/sqrt(32): folds the 1/sqrt(D) softmax scale and exp->exp2 into Q.
#define QSCALE 0.25503486f

__device__ __forceinline__ bf16x8 ldg_frag(const __hip_bfloat16* p) {
    return *reinterpret_cast<const bf16x8*>(p);
}

__device__ __forceinline__ unsigned short bf16_bits(float v) {
    return __builtin_bit_cast(unsigned short, __float2bfloat16(v));
}

__device__ __forceinline__ unsigned pack_bf16(float lo, float hi) {
    return (unsigned)bf16_bits(lo) | ((unsigned)bf16_bits(hi) << 16);
}

// ---------------- f32 -> bf16 conversion into workspace -------------------
__global__ __launch_bounds__(256) void convert_kernel(
    const float* __restrict__ x,  const float* __restrict__ wq,
    const float* __restrict__ wk, const float* __restrict__ wv,
    const float* __restrict__ er,
    __hip_bfloat16* __restrict__ xb, __hip_bfloat16* __restrict__ wb,
    __hip_bfloat16* __restrict__ erb)
{
    const int GX = 1048576, GW = 65536, GE = 16376;  // in float4 groups
    int g = blockIdx.x * 256 + threadIdx.x;
    if (g >= GX + 3 * GW + GE) return;
    const float* src;
    __hip_bfloat16* dst;
    int rel;
    if (g < GX)               { src = x;  dst = xb;          rel = g; }
    else if (g < GX +   GW)   { src = wq; dst = wb;          rel = g - GX; }
    else if (g < GX + 2*GW)   { src = wk; dst = wb + 262144; rel = g - GX - GW; }
    else if (g < GX + 3*GW)   { src = wv; dst = wb + 524288; rel = g - GX - 2*GW; }
    else                      { src = er; dst = erb;         rel = g - GX - 3*GW; }
    const float4 v = *reinterpret_cast<const float4*>(src + (size_t)rel * 4);
    u16x4 pk;
    pk[0] = bf16_bits(v.x);
    pk[1] = bf16_bits(v.y);
    pk[2] = bf16_bits(v.z);
    pk[3] = bf16_bits(v.w);
    *reinterpret_cast<u16x4*>(dst + (size_t)rel * 4) = pk;
}

// ---------------- projection: Q/K/V = x @ W^T ------------------------------
// grid (6,128): WG = 64 rows x 256 cols of [Q|K|V]; wave = 64x64.
// V epilogue writes the INTERLEAVED layout Vti: u32[d][512], where u32 slot
// (s>>5)*16 + (s&15) packs bf16 pair ( V[s], V[s+16] ) of the 32-block.
__global__ __launch_bounds__(256) void proj_kernel(
    const __hip_bfloat16* __restrict__ xb,   // [8192][512]
    const __hip_bfloat16* __restrict__ wb,   // [1536][512]
    __hip_bfloat16* __restrict__ Qs,   // [B][H][S][D], scaled by QSCALE
    __hip_bfloat16* __restrict__ Kh,   // [B][H][S][D]
    unsigned* __restrict__ Vt32)       // [B][H][D][512 u32] interleaved
{
    const int tid  = threadIdx.x;
    const int wave = tid >> 6;
    const int lane = tid & 63;
    const int li   = lane & 15;
    const int quad = lane >> 4;

    const int m0    = blockIdx.y * 64;
    const int nbase = blockIdx.x * 256 + wave * 64;   // multiple of 64

    f32x4 acc[4][4];
    #pragma unroll
    for (int rf = 0; rf < 4; ++rf)
        #pragma unroll
        for (int t = 0; t < 4; ++t) acc[rf][t] = f32x4{0.f, 0.f, 0.f, 0.f};

    const __hip_bfloat16* xp = xb + (size_t)(m0 + li) * Ee + quad * 8;
    const __hip_bfloat16* wp = wb + (size_t)(nbase + li) * Ee + quad * 8;

    for (int k0 = 0; k0 < Ee; k0 += 32) {
        bf16x8 a[4], bfr[4];
        #pragma unroll
        for (int rf = 0; rf < 4; ++rf) a[rf]  = ldg_frag(xp + rf * 16 * Ee + k0);
        #pragma unroll
        for (int t = 0; t < 4; ++t)    bfr[t] = ldg_frag(wp + t * 16 * Ee + k0);
        #pragma unroll
        for (int rf = 0; rf < 4; ++rf)
            #pragma unroll
            for (int t = 0; t < 4; ++t)
                acc[rf][t] = __builtin_amdgcn_mfma_f32_16x16x32_bf16(
                    a[rf], bfr[t], acc[rf][t], 0, 0, 0);
    }

    // epilogue. C layout: col = li, row = quad*4 + reg.
    const int mat = nbase >> 9;        // 0=Q 1=K 2=V (uniform per wave)
    const int nn0 = nbase & 511;
    const int bb  = m0 >> 10;          // 64-row block never straddles b
    const int sb  = m0 & 1023;
    if (mat == 2) {
        #pragma unroll
        for (int t = 0; t < 4; ++t) {
            int nn = nn0 + t * 16 + li;
            int h = nn >> 5, d = nn & 31;
            size_t base = ((size_t)(bb * Hh + h) * Dd + d) * 512
                        + (sb >> 5) * 16 + quad * 4;
            #pragma unroll
            for (int p = 0; p < 2; ++p) {      // rf pair (2p, 2p+1)
                u32x4 pk;
                #pragma unroll
                for (int r = 0; r < 4; ++r)
                    pk[r] = pack_bf16(acc[2*p][t][r], acc[2*p+1][t][r]);
                *reinterpret_cast<u32x4*>(Vt32 + base + (size_t)p * 16) = pk;
            }
        }
    } else {
        __hip_bfloat16* dst = (mat == 0) ? Qs : Kh;
        const float sc = (mat == 0) ? QSCALE : 1.0f;
        #pragma unroll
        for (int rf = 0; rf < 4; ++rf) {
            const int srow = sb + rf * 16 + quad * 4;
            #pragma unroll
            for (int t = 0; t < 4; ++t) {
                int nn = nn0 + t * 16 + li;
                int h = nn >> 5, d = nn & 31;
                #pragma unroll
                for (int r = 0; r < 4; ++r)
                    dst[((size_t)(bb * Hh + h) * Ss + (srow + r)) * Dd + d] =
                        __float2bfloat16(acc[rf][t][r] * sc);
            }
        }
    }
}

// ---------------- attention -----------------------------------------------
// grid 2048 = B*H*(S/64); 4 waves/WG, wave owns a 16-row Q strip.
// qr: col-major stride 19 (odd) -> skew gather provably <=2-way conflicts.
// P: packed u32 (p(i,j), p(i,j+16)) stride 20 u32; PV MFMA uses permuted
// k-order j(k=8q+2t+s) = 4q+t+16s, matched by the interleaved Vti layout.
__global__ __launch_bounds__(256, 8) void attn_kernel(
    const __hip_bfloat16* __restrict__ Qs,
    const __hip_bfloat16* __restrict__ Kh,
    const __hip_bfloat16* __restrict__ Vt,   // bf16 view of Vti (same bytes)
    const __hip_bfloat16* __restrict__ Er,   // [2047][32] bf16 (ws)
    float* __restrict__ out)                 // [B][S][E] f32
{
    const int tid  = threadIdx.x;
    const int wave = tid >> 6;
    const int lane = tid & 63;
    const int li   = lane & 15;
    const int quad = lane >> 4;

    const int wg = blockIdx.x;
    const int ib = wg & 15;
    const int h  = (wg >> 4) & 15;
    const int b  = wg >> 8;
    const int i0 = ib * 64 + wave * 16;

    const __hip_bfloat16* Qp = Qs + (size_t)(b * Hh + h) * Ss * Dd;
    const __hip_bfloat16* Kp = Kh + (size_t)(b * Hh + h) * Ss * Dd;
    const __hip_bfloat16* Vp = Vt + (size_t)(b * Hh + h) * Dd * Ss;

    __shared__ float    qr_lds[4][47 * 19];   // 3572 B / wave
    __shared__ unsigned pb_lds[4][16 * 20];   // 1280 B / wave (19408 total)
    float*    qr = qr_lds[wave];
    unsigned* pb = pb_lds[wave];

    const bf16x8 qfrag = ldg_frag(Qp + (i0 + li) * Dd + quad * 8);

    // loop-invariant LDS index bases
    const int wb0 = li * 19 + quad * 4;                  // qr block-0 write
    const int gA  = (li - quad * 4 + 15) * 19 + quad * 4;// gather base (r=0)
    const int pbw = quad * 4 * 20 + li;                  // pb write base
    const int pbr = li * 20 + quad * 4;                  // pb read (16B align)

    f32x4 o0 = f32x4{0.f, 0.f, 0.f, 0.f};   // d = 0..15
    f32x4 o1 = f32x4{0.f, 0.f, 0.f, 0.f};   // d = 16..31
    float lsum[4] = {0.f, 0.f, 0.f, 0.f};
    const f32x4 zero = f32x4{0.f, 0.f, 0.f, 0.f};

    for (int j0 = 0; j0 < Ss; j0 += 32) {
        bf16x8 k0f = ldg_frag(Kp + (j0 + li) * Dd + quad * 8);
        bf16x8 k1f = ldg_frag(Kp + (j0 + 16 + li) * Dd + quad * 8);
        const int rbase = j0 - i0 + 1008;     // >= 0 always
        bf16x8 e0 = ldg_frag(Er + (rbase + li) * Dd + quad * 8);
        bf16x8 e1 = ldg_frag(Er + (rbase + 16 + li) * Dd + quad * 8);
        bf16x8 e2 = ldg_frag(Er + min(rbase + 32 + li, 2046) * Dd + quad * 8);
        // V interleaved: same byte addressing as plain transposed layout
        bf16x8 v0 = ldg_frag(Vp + (li     ) * Ss + j0 + quad * 8);
        bf16x8 v1 = ldg_frag(Vp + (li + 16) * Ss + j0 + quad * 8);

        f32x4 s0  = __builtin_amdgcn_mfma_f32_16x16x32_bf16(qfrag, k0f, zero, 0, 0, 0);
        f32x4 s1  = __builtin_amdgcn_mfma_f32_16x16x32_bf16(qfrag, k1f, zero, 0, 0, 0);
        f32x4 qr0 = __builtin_amdgcn_mfma_f32_16x16x32_bf16(qfrag, e0, zero, 0, 0, 0);
        f32x4 qr1 = __builtin_amdgcn_mfma_f32_16x16x32_bf16(qfrag, e1, zero, 0, 0, 0);
        f32x4 qr2 = __builtin_amdgcn_mfma_f32_16x16x32_bf16(qfrag, e2, zero, 0, 0, 0);

        // qr writes: col-major stride 19, 4 consecutive dwords per block
        // (compiler combines to ds_write2_b32 pairs; <=3-way conflicts)
        #pragma unroll
        for (int r = 0; r < 4; ++r) qr[wb0 + r]       = qr0[r];
        #pragma unroll
        for (int r = 0; r < 4; ++r) qr[wb0 + 304 + r] = qr1[r];   // +16*19
        if (li < 15) {                                            // col 47 unused
            #pragma unroll
            for (int r = 0; r < 4; ++r) qr[wb0 + 608 + r] = qr2[r]; // +32*19
        }

        // skew gather (<=2-way), exp2 softmax, pack P pairs (j, j+16)
        float p0[4], p1[4];
        #pragma unroll
        for (int r = 0; r < 4; ++r) {
            float srel0 = qr[gA - 18 * r];          // bandcol li-row+15
            float srel1 = qr[gA + 304 - 18 * r];    // bandcol +16
            p0[r] = EXP2F(s0[r] + srel0);
            p1[r] = EXP2F(s1[r] + srel1);
            lsum[r] += p0[r] + p1[r];
        }
        #pragma unroll
        for (int r = 0; r < 4; ++r)
            pb[pbw + 20 * r] = pack_bf16(p0[r], p1[r]);

        // PV with permuted k: A-frag = 4 u32 (8 bf16) contiguous, 16B aligned
        bf16x8 pfrag = *reinterpret_cast<const bf16x8*>(&pb[pbr]);
        o0 = __builtin_amdgcn_mfma_f32_16x16x32_bf16(pfrag, v0, o0, 0, 0, 0);
        o1 = __builtin_amdgcn_mfma_f32_16x16x32_bf16(pfrag, v1, o1, 0, 0, 0);
    }

    // reduce row sums across the 16 lanes of each quad-group
    #pragma unroll
    for (int r = 0; r < 4; ++r) {
        float v = lsum[r];
        v += __shfl_xor(v, 1, 64);
        v += __shfl_xor(v, 2, 64);
        v += __shfl_xor(v, 4, 64);
        v += __shfl_xor(v, 8, 64);
        lsum[r] = 1.0f / v;
    }
    #pragma unroll
    for (int r = 0; r < 4; ++r) {
        const int srow = i0 + quad * 4 + r;
        float* op = out + ((size_t)b * Ss + srow) * Ee + h * Dd;
        op[li]      = o0[r] * lsum[r];
        op[16 + li] = o1[r] * lsum[r];
    }
}

extern "C" void kernel_launch(void* const* d_in, const int* in_sizes, int n_in,
                              void* d_out, int out_size, void* d_ws, size_t ws_size,
                              hipStream_t stream) {
    const float* x  = (const float*)d_in[0];
    const float* Wq = (const float*)d_in[1];
    const float* Wk = (const float*)d_in[2];
    const float* Wv = (const float*)d_in[3];
    const float* Er = (const float*)d_in[4];
    float* out = (float*)d_out;

    // ws layout (bf16 elements; all offsets 16B-aligned)
    __hip_bfloat16* xb  = reinterpret_cast<__hip_bfloat16*>(d_ws);
    __hip_bfloat16* wbb = xb  + (size_t)8192 * 512;
    __hip_bfloat16* erb = wbb + (size_t)1536 * 512;
    __hip_bfloat16* Qs  = erb + 65536;
    __hip_bfloat16* Kh  = Qs  + (size_t)Bb * Hh * Ss * Dd;
    __hip_bfloat16* Vt  = Kh  + (size_t)Bb * Hh * Ss * Dd;

    convert_kernel<<<4929, 256, 0, stream>>>(x, Wq, Wk, Wv, Er, xb, wbb, erb);
    proj_kernel<<<dim3(6, 128), 256, 0, stream>>>(
        xb, wbb, Qs, Kh, reinterpret_cast<unsigned*>(Vt));
    attn_kernel<<<dim3(2048), 256, 0, stream>>>(Qs, Kh, Vt, erb, out);
}

// Round 5
// 249.387 us; speedup vs baseline: 1.1227x; 1.1227x over previous
//
#include <hip/hip_runtime.h>
#include <hip/hip_bf16.h>

// LocalAttn: B=8 S=1024 E=512 H=16 D=32, rel-pos bias, NO causal mask.
// f32 inputs / f32 output. Internals bf16 for MFMA.
// R5: Srel skew gather via ds_bpermute (no qr LDS buffer, no bank
// conflicts), j-loop unrolled x64 (two 32-chunks share Er band blocks),
// XCD-aware block swizzle, plain launch_bounds (R4's (256,8) caused
// VGPR=32 spills: WRITE_SIZE 16->34 MB).

typedef short bf16x8 __attribute__((ext_vector_type(8)));   // 8 bf16 (4 VGPRs)
typedef float f32x4 __attribute__((ext_vector_type(4)));
typedef unsigned short u16x4 __attribute__((ext_vector_type(4)));
typedef unsigned int u32x4 __attribute__((ext_vector_type(4)));

#if __has_builtin(__builtin_amdgcn_exp2f)
#define EXP2F(x) __builtin_amdgcn_exp2f(x)
#else
#define EXP2F(x) exp2f(x)
#endif

constexpr int Bb = 8, Ss = 1024, Ee = 512, Hh = 16, Dd = 32;
// log2(e)/sqrt(32): folds the 1/sqrt(D) softmax scale and exp->exp2 into Q.
#define QSCALE 0.25503486f

__device__ __forceinline__ bf16x8 ldg_frag(const __hip_bfloat16* p) {
    return *reinterpret_cast<const bf16x8*>(p);
}

__device__ __forceinline__ unsigned short bf16_bits(float v) {
    return __builtin_bit_cast(unsigned short, __float2bfloat16(v));
}

__device__ __forceinline__ unsigned pack_bf16(float lo, float hi) {
    return (unsigned)bf16_bits(lo) | ((unsigned)bf16_bits(hi) << 16);
}

__device__ __forceinline__ float bperm_f(int addr, float v) {
    return __builtin_bit_cast(float,
        __builtin_amdgcn_ds_bpermute(addr, __builtin_bit_cast(int, v)));
}

// ---------------- f32 -> bf16 conversion into workspace -------------------
__global__ __launch_bounds__(256) void convert_kernel(
    const float* __restrict__ x,  const float* __restrict__ wq,
    const float* __restrict__ wk, const float* __restrict__ wv,
    const float* __restrict__ er,
    __hip_bfloat16* __restrict__ xb, __hip_bfloat16* __restrict__ wb,
    __hip_bfloat16* __restrict__ erb)
{
    const int GX = 1048576, GW = 65536, GE = 16376;  // in float4 groups
    int g = blockIdx.x * 256 + threadIdx.x;
    if (g >= GX + 3 * GW + GE) return;
    const float* src;
    __hip_bfloat16* dst;
    int rel;
    if (g < GX)               { src = x;  dst = xb;          rel = g; }
    else if (g < GX +   GW)   { src = wq; dst = wb;          rel = g - GX; }
    else if (g < GX + 2*GW)   { src = wk; dst = wb + 262144; rel = g - GX - GW; }
    else if (g < GX + 3*GW)   { src = wv; dst = wb + 524288; rel = g - GX - 2*GW; }
    else                      { src = er; dst = erb;         rel = g - GX - 3*GW; }
    const float4 v = *reinterpret_cast<const float4*>(src + (size_t)rel * 4);
    u16x4 pk;
    pk[0] = bf16_bits(v.x);
    pk[1] = bf16_bits(v.y);
    pk[2] = bf16_bits(v.z);
    pk[3] = bf16_bits(v.w);
    *reinterpret_cast<u16x4*>(dst + (size_t)rel * 4) = pk;
}

// ---------------- projection: Q/K/V = x @ W^T ------------------------------
// grid (6,128): WG = 64 rows x 256 cols of [Q|K|V]; wave = 64x64.
// V epilogue writes INTERLEAVED Vti: u32[d][512], slot (s>>5)*16+(s&15)
// packs the bf16 pair (V[s], V[s+16]) of each 32-block.
__global__ __launch_bounds__(256) void proj_kernel(
    const __hip_bfloat16* __restrict__ xb,   // [8192][512]
    const __hip_bfloat16* __restrict__ wb,   // [1536][512]
    __hip_bfloat16* __restrict__ Qs,   // [B][H][S][D], scaled by QSCALE
    __hip_bfloat16* __restrict__ Kh,   // [B][H][S][D]
    unsigned* __restrict__ Vt32)       // [B][H][D][512 u32] interleaved
{
    const int tid  = threadIdx.x;
    const int wave = tid >> 6;
    const int lane = tid & 63;
    const int li   = lane & 15;
    const int quad = lane >> 4;

    const int m0    = blockIdx.y * 64;
    const int nbase = blockIdx.x * 256 + wave * 64;   // multiple of 64

    f32x4 acc[4][4];
    #pragma unroll
    for (int rf = 0; rf < 4; ++rf)
        #pragma unroll
        for (int t = 0; t < 4; ++t) acc[rf][t] = f32x4{0.f, 0.f, 0.f, 0.f};

    const __hip_bfloat16* xp = xb + (size_t)(m0 + li) * Ee + quad * 8;
    const __hip_bfloat16* wp = wb + (size_t)(nbase + li) * Ee + quad * 8;

    for (int k0 = 0; k0 < Ee; k0 += 32) {
        bf16x8 a[4], bfr[4];
        #pragma unroll
        for (int rf = 0; rf < 4; ++rf) a[rf]  = ldg_frag(xp + rf * 16 * Ee + k0);
        #pragma unroll
        for (int t = 0; t < 4; ++t)    bfr[t] = ldg_frag(wp + t * 16 * Ee + k0);
        #pragma unroll
        for (int rf = 0; rf < 4; ++rf)
            #pragma unroll
            for (int t = 0; t < 4; ++t)
                acc[rf][t] = __builtin_amdgcn_mfma_f32_16x16x32_bf16(
                    a[rf], bfr[t], acc[rf][t], 0, 0, 0);
    }

    // epilogue. C layout: col = li, row = quad*4 + reg.
    const int mat = nbase >> 9;        // 0=Q 1=K 2=V (uniform per wave)
    const int nn0 = nbase & 511;
    const int bb  = m0 >> 10;          // 64-row block never straddles b
    const int sb  = m0 & 1023;
    if (mat == 2) {
        #pragma unroll
        for (int t = 0; t < 4; ++t) {
            int nn = nn0 + t * 16 + li;
            int h = nn >> 5, d = nn & 31;
            size_t base = ((size_t)(bb * Hh + h) * Dd + d) * 512
                        + (sb >> 5) * 16 + quad * 4;
            #pragma unroll
            for (int p = 0; p < 2; ++p) {      // rf pair (2p, 2p+1)
                u32x4 pk;
                #pragma unroll
                for (int r = 0; r < 4; ++r)
                    pk[r] = pack_bf16(acc[2*p][t][r], acc[2*p+1][t][r]);
                *reinterpret_cast<u32x4*>(Vt32 + base + (size_t)p * 16) = pk;
            }
        }
    } else {
        __hip_bfloat16* dst = (mat == 0) ? Qs : Kh;
        const float sc = (mat == 0) ? QSCALE : 1.0f;
        #pragma unroll
        for (int rf = 0; rf < 4; ++rf) {
            const int srow = sb + rf * 16 + quad * 4;
            #pragma unroll
            for (int t = 0; t < 4; ++t) {
                int nn = nn0 + t * 16 + li;
                int h = nn >> 5, d = nn & 31;
                #pragma unroll
                for (int r = 0; r < 4; ++r)
                    dst[((size_t)(bb * Hh + h) * Ss + (srow + r)) * Dd + d] =
                        __float2bfloat16(acc[rf][t][r] * sc);
            }
        }
    }
}

// ---------------- attention -----------------------------------------------
// grid 2048; swizzle: head (b,h) = blockIdx&127 -> XCD = h&7 fixed (16
// heads x 192 KB QKV per XCD L2). Wave owns a 16-row Q strip; j-loop
// steps 64 (two 32-chunks A/B sharing Er band block 2 == B's block 0).
// Srel: band MFMA C-frags rotated intra-quad via ds_bpermute (conflict-
// free, no LDS buffer). P round-trips tiny pb buffer (stride 20, 2-way).
__global__ __launch_bounds__(256) void attn_kernel(
    const __hip_bfloat16* __restrict__ Qs,
    const __hip_bfloat16* __restrict__ Kh,
    const __hip_bfloat16* __restrict__ Vt,   // bf16 view of Vti (same bytes)
    const __hip_bfloat16* __restrict__ Er,   // [2047][32] bf16 (+1 pad row)
    float* __restrict__ out)                 // [B][S][E] f32
{
    const int tid  = threadIdx.x;
    const int wave = tid >> 6;
    const int lane = tid & 63;
    const int li   = lane & 15;
    const int quad = lane >> 4;

    const int c  = blockIdx.x & 127;
    const int b  = c >> 4;
    const int h  = c & 15;
    const int ib = blockIdx.x >> 7;
    const int i0 = ib * 64 + wave * 16;

    const __hip_bfloat16* Qp = Qs + (size_t)(b * Hh + h) * Ss * Dd;
    const __hip_bfloat16* Kp = Kh + (size_t)(b * Hh + h) * Ss * Dd;
    const __hip_bfloat16* Vp = Vt + (size_t)(b * Hh + h) * Dd * Ss;

    __shared__ unsigned pb_lds[4][2][16 * 20];   // 10240 B total
    unsigned* pbA = pb_lds[wave][0];
    unsigned* pbB = pb_lds[wave][1];

    const bf16x8 qfrag = ldg_frag(Qp + (i0 + li) * Dd + quad * 8);

    // loop-invariant: bpermute byte-addresses and row-compare masks.
    // band element (row, bc=li-row+15): lane 16*quad + (bc&15), reg row&3.
    int addr4[4];
    bool cond[4];
    #pragma unroll
    for (int r = 0; r < 4; ++r) {
        const int row = quad * 4 + r;
        addr4[r] = (16 * quad + ((li - row + 15) & 15)) * 4;
        cond[r]  = (li <= row);            // bc < 16 -> lower band block
    }
    const int pbw = quad * 80 + li;        // pb write base (u32)
    const int pbr = li * 20 + quad * 4;    // pb read base (16B aligned)

    f32x4 o0 = f32x4{0.f, 0.f, 0.f, 0.f};   // d = 0..15
    f32x4 o1 = f32x4{0.f, 0.f, 0.f, 0.f};   // d = 16..31
    float lsum[4] = {0.f, 0.f, 0.f, 0.f};
    const f32x4 zero = f32x4{0.f, 0.f, 0.f, 0.f};

    for (int j0 = 0; j0 < Ss; j0 += 64) {
        // ---- global loads (K, Er first; V last so vmcnt waits overlap) ----
        bf16x8 kA0 = ldg_frag(Kp + (j0      + li) * Dd + quad * 8);
        bf16x8 kA1 = ldg_frag(Kp + (j0 + 16 + li) * Dd + quad * 8);
        bf16x8 kB0 = ldg_frag(Kp + (j0 + 32 + li) * Dd + quad * 8);
        bf16x8 kB1 = ldg_frag(Kp + (j0 + 48 + li) * Dd + quad * 8);
        const int rbase = j0 - i0 + 1008;    // >= 0; max row 2047 = pad row
        bf16x8 e0 = ldg_frag(Er + (rbase      + li) * Dd + quad * 8);
        bf16x8 e1 = ldg_frag(Er + (rbase + 16 + li) * Dd + quad * 8);
        bf16x8 e2 = ldg_frag(Er + (rbase + 32 + li) * Dd + quad * 8);
        bf16x8 e3 = ldg_frag(Er + (rbase + 48 + li) * Dd + quad * 8);
        bf16x8 e4 = ldg_frag(Er + (rbase + 64 + li) * Dd + quad * 8);
        bf16x8 vA0 = ldg_frag(Vp + (li     ) * Ss + j0 + quad * 8);
        bf16x8 vA1 = ldg_frag(Vp + (li + 16) * Ss + j0 + quad * 8);
        bf16x8 vB0 = ldg_frag(Vp + (li     ) * Ss + j0 + 32 + quad * 8);
        bf16x8 vB1 = ldg_frag(Vp + (li + 16) * Ss + j0 + 32 + quad * 8);

        // ---- scores ----
        f32x4 sA0 = __builtin_amdgcn_mfma_f32_16x16x32_bf16(qfrag, kA0, zero, 0, 0, 0);
        f32x4 sA1 = __builtin_amdgcn_mfma_f32_16x16x32_bf16(qfrag, kA1, zero, 0, 0, 0);
        f32x4 sB0 = __builtin_amdgcn_mfma_f32_16x16x32_bf16(qfrag, kB0, zero, 0, 0, 0);
        f32x4 sB1 = __builtin_amdgcn_mfma_f32_16x16x32_bf16(qfrag, kB1, zero, 0, 0, 0);
        f32x4 q0 = __builtin_amdgcn_mfma_f32_16x16x32_bf16(qfrag, e0, zero, 0, 0, 0);
        f32x4 q1 = __builtin_amdgcn_mfma_f32_16x16x32_bf16(qfrag, e1, zero, 0, 0, 0);
        f32x4 q2 = __builtin_amdgcn_mfma_f32_16x16x32_bf16(qfrag, e2, zero, 0, 0, 0);
        f32x4 q3 = __builtin_amdgcn_mfma_f32_16x16x32_bf16(qfrag, e3, zero, 0, 0, 0);
        f32x4 q4 = __builtin_amdgcn_mfma_f32_16x16x32_bf16(qfrag, e4, zero, 0, 0, 0);

        // ---- Srel rotate + exp2 softmax (unnormalized) ----
        float pA0[4], pA1[4], pB0[4], pB1[4];
        #pragma unroll
        for (int r = 0; r < 4; ++r) {
            float f0 = bperm_f(addr4[r], q0[r]);
            float f1 = bperm_f(addr4[r], q1[r]);
            float f2 = bperm_f(addr4[r], q2[r]);
            float f3 = bperm_f(addr4[r], q3[r]);
            float f4 = bperm_f(addr4[r], q4[r]);
            float srA0 = cond[r] ? f0 : f1;
            float srA1 = cond[r] ? f1 : f2;
            float srB0 = cond[r] ? f2 : f3;
            float srB1 = cond[r] ? f3 : f4;
            pA0[r] = EXP2F(sA0[r] + srA0);
            pA1[r] = EXP2F(sA1[r] + srA1);
            pB0[r] = EXP2F(sB0[r] + srB0);
            pB1[r] = EXP2F(sB1[r] + srB1);
            lsum[r] += (pA0[r] + pA1[r]) + (pB0[r] + pB1[r]);
        }
        #pragma unroll
        for (int r = 0; r < 4; ++r) {
            pbA[pbw + 20 * r] = pack_bf16(pA0[r], pA1[r]);
            pbB[pbw + 20 * r] = pack_bf16(pB0[r], pB1[r]);
        }

        // ---- PV (k-permuted A-frag matches interleaved Vti) ----
        bf16x8 pfA = *reinterpret_cast<const bf16x8*>(&pbA[pbr]);
        bf16x8 pfB = *reinterpret_cast<const bf16x8*>(&pbB[pbr]);
        o0 = __builtin_amdgcn_mfma_f32_16x16x32_bf16(pfA, vA0, o0, 0, 0, 0);
        o1 = __builtin_amdgcn_mfma_f32_16x16x32_bf16(pfA, vA1, o1, 0, 0, 0);
        o0 = __builtin_amdgcn_mfma_f32_16x16x32_bf16(pfB, vB0, o0, 0, 0, 0);
        o1 = __builtin_amdgcn_mfma_f32_16x16x32_bf16(pfB, vB1, o1, 0, 0, 0);
    }

    // reduce row sums across the 16 lanes of each quad-group
    #pragma unroll
    for (int r = 0; r < 4; ++r) {
        float v = lsum[r];
        v += __shfl_xor(v, 1, 64);
        v += __shfl_xor(v, 2, 64);
        v += __shfl_xor(v, 4, 64);
        v += __shfl_xor(v, 8, 64);
        lsum[r] = 1.0f / v;
    }
    #pragma unroll
    for (int r = 0; r < 4; ++r) {
        const int srow = i0 + quad * 4 + r;
        float* op = out + ((size_t)b * Ss + srow) * Ee + h * Dd;
        op[li]      = o0[r] * lsum[r];
        op[16 + li] = o1[r] * lsum[r];
    }
}

extern "C" void kernel_launch(void* const* d_in, const int* in_sizes, int n_in,
                              void* d_out, int out_size, void* d_ws, size_t ws_size,
                              hipStream_t stream) {
    const float* x  = (const float*)d_in[0];
    const float* Wq = (const float*)d_in[1];
    const float* Wk = (const float*)d_in[2];
    const float* Wv = (const float*)d_in[3];
    const float* Er = (const float*)d_in[4];
    float* out = (float*)d_out;

    // ws layout (bf16 elements; all offsets 16B-aligned)
    __hip_bfloat16* xb  = reinterpret_cast<__hip_bfloat16*>(d_ws);
    __hip_bfloat16* wbb = xb  + (size_t)8192 * 512;
    __hip_bfloat16* erb = wbb + (size_t)1536 * 512;
    __hip_bfloat16* Qs  = erb + 65536;                  // row 2047 = pad
    __hip_bfloat16* Kh  = Qs  + (size_t)Bb * Hh * Ss * Dd;
    __hip_bfloat16* Vt  = Kh  + (size_t)Bb * Hh * Ss * Dd;

    convert_kernel<<<4929, 256, 0, stream>>>(x, Wq, Wk, Wv, Er, xb, wbb, erb);
    proj_kernel<<<dim3(6, 128), 256, 0, stream>>>(
        xb, wbb, Qs, Kh, reinterpret_cast<unsigned*>(Vt));
    attn_kernel<<<dim3(2048), 256, 0, stream>>>(Qs, Kh, Vt, erb, out);
}

// Round 6
// 194.507 us; speedup vs baseline: 1.4395x; 1.2821x over previous
//
#include <hip/hip_runtime.h>
#include <hip/hip_bf16.h>

// LocalAttn: B=8 S=1024 E=512 H=16 D=32, rel-pos bias, NO causal mask.
// f32 inputs / f32 output. Internals bf16 for MFMA.
// R6: attn processes TWO 16-row Q strips per wave (32 rows): K/V loads
// shared, Er band windows overlap (strip2 block n == strip1 block n-1,
// +1 load), 14 loads : 26 MFMAs per iter (was 13:13). Grid 1024.
// proj/convert deliberately UNCHANGED from R5 (probe: is the constant
// ~110us residual proj or harness overhead?).

typedef short bf16x8 __attribute__((ext_vector_type(8)));   // 8 bf16 (4 VGPRs)
typedef float f32x4 __attribute__((ext_vector_type(4)));
typedef unsigned short u16x4 __attribute__((ext_vector_type(4)));
typedef unsigned int u32x4 __attribute__((ext_vector_type(4)));

#if __has_builtin(__builtin_amdgcn_exp2f)
#define EXP2F(x) __builtin_amdgcn_exp2f(x)
#else
#define EXP2F(x) exp2f(x)
#endif

constexpr int Bb = 8, Ss = 1024, Ee = 512, Hh = 16, Dd = 32;
// log2(e)/sqrt(32): folds the 1/sqrt(D) softmax scale and exp->exp2 into Q.
#define QSCALE 0.25503486f

__device__ __forceinline__ bf16x8 ldg_frag(const __hip_bfloat16* p) {
    return *reinterpret_cast<const bf16x8*>(p);
}

__device__ __forceinline__ unsigned short bf16_bits(float v) {
    return __builtin_bit_cast(unsigned short, __float2bfloat16(v));
}

__device__ __forceinline__ unsigned pack_bf16(float lo, float hi) {
    return (unsigned)bf16_bits(lo) | ((unsigned)bf16_bits(hi) << 16);
}

__device__ __forceinline__ float bperm_f(int addr, float v) {
    return __builtin_bit_cast(float,
        __builtin_amdgcn_ds_bpermute(addr, __builtin_bit_cast(int, v)));
}

// ---------------- f32 -> bf16 conversion into workspace -------------------
__global__ __launch_bounds__(256) void convert_kernel(
    const float* __restrict__ x,  const float* __restrict__ wq,
    const float* __restrict__ wk, const float* __restrict__ wv,
    const float* __restrict__ er,
    __hip_bfloat16* __restrict__ xb, __hip_bfloat16* __restrict__ wb,
    __hip_bfloat16* __restrict__ erb)
{
    const int GX = 1048576, GW = 65536, GE = 16376;  // in float4 groups
    int g = blockIdx.x * 256 + threadIdx.x;
    if (g >= GX + 3 * GW + GE) return;
    const float* src;
    __hip_bfloat16* dst;
    int rel;
    if (g < GX)               { src = x;  dst = xb;          rel = g; }
    else if (g < GX +   GW)   { src = wq; dst = wb;          rel = g - GX; }
    else if (g < GX + 2*GW)   { src = wk; dst = wb + 262144; rel = g - GX - GW; }
    else if (g < GX + 3*GW)   { src = wv; dst = wb + 524288; rel = g - GX - 2*GW; }
    else                      { src = er; dst = erb;         rel = g - GX - 3*GW; }
    const float4 v = *reinterpret_cast<const float4*>(src + (size_t)rel * 4);
    u16x4 pk;
    pk[0] = bf16_bits(v.x);
    pk[1] = bf16_bits(v.y);
    pk[2] = bf16_bits(v.z);
    pk[3] = bf16_bits(v.w);
    *reinterpret_cast<u16x4*>(dst + (size_t)rel * 4) = pk;
}

// ---------------- projection: Q/K/V = x @ W^T ------------------------------
// grid (6,128): WG = 64 rows x 256 cols of [Q|K|V]; wave = 64x64.
// V epilogue writes INTERLEAVED Vti: u32[d][512], slot (s>>5)*16+(s&15)
// packs the bf16 pair (V[s], V[s+16]) of each 32-block.
__global__ __launch_bounds__(256) void proj_kernel(
    const __hip_bfloat16* __restrict__ xb,   // [8192][512]
    const __hip_bfloat16* __restrict__ wb,   // [1536][512]
    __hip_bfloat16* __restrict__ Qs,   // [B][H][S][D], scaled by QSCALE
    __hip_bfloat16* __restrict__ Kh,   // [B][H][S][D]
    unsigned* __restrict__ Vt32)       // [B][H][D][512 u32] interleaved
{
    const int tid  = threadIdx.x;
    const int wave = tid >> 6;
    const int lane = tid & 63;
    const int li   = lane & 15;
    const int quad = lane >> 4;

    const int m0    = blockIdx.y * 64;
    const int nbase = blockIdx.x * 256 + wave * 64;   // multiple of 64

    f32x4 acc[4][4];
    #pragma unroll
    for (int rf = 0; rf < 4; ++rf)
        #pragma unroll
        for (int t = 0; t < 4; ++t) acc[rf][t] = f32x4{0.f, 0.f, 0.f, 0.f};

    const __hip_bfloat16* xp = xb + (size_t)(m0 + li) * Ee + quad * 8;
    const __hip_bfloat16* wp = wb + (size_t)(nbase + li) * Ee + quad * 8;

    for (int k0 = 0; k0 < Ee; k0 += 32) {
        bf16x8 a[4], bfr[4];
        #pragma unroll
        for (int rf = 0; rf < 4; ++rf) a[rf]  = ldg_frag(xp + rf * 16 * Ee + k0);
        #pragma unroll
        for (int t = 0; t < 4; ++t)    bfr[t] = ldg_frag(wp + t * 16 * Ee + k0);
        #pragma unroll
        for (int rf = 0; rf < 4; ++rf)
            #pragma unroll
            for (int t = 0; t < 4; ++t)
                acc[rf][t] = __builtin_amdgcn_mfma_f32_16x16x32_bf16(
                    a[rf], bfr[t], acc[rf][t], 0, 0, 0);
    }

    // epilogue. C layout: col = li, row = quad*4 + reg.
    const int mat = nbase >> 9;        // 0=Q 1=K 2=V (uniform per wave)
    const int nn0 = nbase & 511;
    const int bb  = m0 >> 10;          // 64-row block never straddles b
    const int sb  = m0 & 1023;
    if (mat == 2) {
        #pragma unroll
        for (int t = 0; t < 4; ++t) {
            int nn = nn0 + t * 16 + li;
            int h = nn >> 5, d = nn & 31;
            size_t base = ((size_t)(bb * Hh + h) * Dd + d) * 512
                        + (sb >> 5) * 16 + quad * 4;
            #pragma unroll
            for (int p = 0; p < 2; ++p) {      // rf pair (2p, 2p+1)
                u32x4 pk;
                #pragma unroll
                for (int r = 0; r < 4; ++r)
                    pk[r] = pack_bf16(acc[2*p][t][r], acc[2*p+1][t][r]);
                *reinterpret_cast<u32x4*>(Vt32 + base + (size_t)p * 16) = pk;
            }
        }
    } else {
        __hip_bfloat16* dst = (mat == 0) ? Qs : Kh;
        const float sc = (mat == 0) ? QSCALE : 1.0f;
        #pragma unroll
        for (int rf = 0; rf < 4; ++rf) {
            const int srow = sb + rf * 16 + quad * 4;
            #pragma unroll
            for (int t = 0; t < 4; ++t) {
                int nn = nn0 + t * 16 + li;
                int h = nn >> 5, d = nn & 31;
                #pragma unroll
                for (int r = 0; r < 4; ++r)
                    dst[((size_t)(bb * Hh + h) * Ss + (srow + r)) * Dd + d] =
                        __float2bfloat16(acc[rf][t][r] * sc);
            }
        }
    }
}

// ---------------- attention -----------------------------------------------
// grid 1024; (b,h) = blockIdx&127 (XCD-local), ib = blockIdx>>7.
// Wave owns TWO 16-row Q strips (32 rows); j-loop steps 64.
// Loads/iter: 4 K + 6 Er + 4 V = 14 for 26 MFMAs.
// Srel: band MFMA C-frags rotated intra-quad via ds_bpermute (conflict-
// free). P round-trips small pb buffers (stride 20 u32, <=2-way).
__global__ __launch_bounds__(256) void attn_kernel(
    const __hip_bfloat16* __restrict__ Qs,
    const __hip_bfloat16* __restrict__ Kh,
    const __hip_bfloat16* __restrict__ Vt,   // bf16 view of Vti (same bytes)
    const __hip_bfloat16* __restrict__ Er,   // [2048][32] bf16 (row 2047 pad)
    float* __restrict__ out)                 // [B][S][E] f32
{
    const int tid  = threadIdx.x;
    const int wave = tid >> 6;
    const int lane = tid & 63;
    const int li   = lane & 15;
    const int quad = lane >> 4;

    const int c  = blockIdx.x & 127;
    const int b  = c >> 4;
    const int h  = c & 15;
    const int ib = blockIdx.x >> 7;          // 0..7
    const int i0 = ib * 128 + wave * 32;     // strip A rows i0.., B rows i0+16..

    const __hip_bfloat16* Qp = Qs + (size_t)(b * Hh + h) * Ss * Dd;
    const __hip_bfloat16* Kp = Kh + (size_t)(b * Hh + h) * Ss * Dd;
    const __hip_bfloat16* Vp = Vt + (size_t)(b * Hh + h) * Dd * Ss;

    __shared__ unsigned pb_lds[4][4][16 * 20];   // 20480 B total
    unsigned* pbA0 = pb_lds[wave][0];   // strip A cols 0-31
    unsigned* pbA1 = pb_lds[wave][1];   // strip A cols 32-63
    unsigned* pbB0 = pb_lds[wave][2];   // strip B cols 0-31
    unsigned* pbB1 = pb_lds[wave][3];   // strip B cols 32-63

    const bf16x8 qfA = ldg_frag(Qp + (i0      + li) * Dd + quad * 8);
    const bf16x8 qfB = ldg_frag(Qp + (i0 + 16 + li) * Dd + quad * 8);

    // loop-invariant: bpermute byte-addresses and band-half selectors.
    // band element (row, bc=li-row+15): lane 16*quad + (bc&15), reg row&3.
    int addr4[4];
    bool cond[4];
    #pragma unroll
    for (int r = 0; r < 4; ++r) {
        const int row = quad * 4 + r;
        addr4[r] = (16 * quad + ((li - row + 15) & 15)) * 4;
        cond[r]  = (li <= row);            // bc < 16 -> lower band block
    }
    const int pbw = quad * 80 + li;        // pb write base (u32)
    const int pbr = li * 20 + quad * 4;    // pb read base (16B aligned)

    f32x4 oA0 = f32x4{0,0,0,0}, oA1 = f32x4{0,0,0,0};
    f32x4 oB0 = f32x4{0,0,0,0}, oB1 = f32x4{0,0,0,0};
    float lsumA[4] = {0,0,0,0}, lsumB[4] = {0,0,0,0};
    const f32x4 zero = f32x4{0,0,0,0};

    for (int j0 = 0; j0 < Ss; j0 += 64) {
        // ---- shared global loads ----
        bf16x8 k0 = ldg_frag(Kp + (j0      + li) * Dd + quad * 8);
        bf16x8 k1 = ldg_frag(Kp + (j0 + 16 + li) * Dd + quad * 8);
        bf16x8 k2 = ldg_frag(Kp + (j0 + 32 + li) * Dd + quad * 8);
        bf16x8 k3 = ldg_frag(Kp + (j0 + 48 + li) * Dd + quad * 8);
        const int rb = j0 - i0 + 1008;       // strip A base; rb-16 >= 0
        bf16x8 em = ldg_frag(Er + (rb - 16 + li) * Dd + quad * 8);
        bf16x8 e0 = ldg_frag(Er + (rb      + li) * Dd + quad * 8);
        bf16x8 e1 = ldg_frag(Er + (rb + 16 + li) * Dd + quad * 8);
        bf16x8 e2 = ldg_frag(Er + (rb + 32 + li) * Dd + quad * 8);
        bf16x8 e3 = ldg_frag(Er + (rb + 48 + li) * Dd + quad * 8);
        bf16x8 e4 = ldg_frag(Er + (rb + 64 + li) * Dd + quad * 8);
        bf16x8 v0 = ldg_frag(Vp + (li     ) * Ss + j0 + quad * 8);
        bf16x8 v1 = ldg_frag(Vp + (li + 16) * Ss + j0 + quad * 8);
        bf16x8 v2 = ldg_frag(Vp + (li     ) * Ss + j0 + 32 + quad * 8);
        bf16x8 v3 = ldg_frag(Vp + (li + 16) * Ss + j0 + 32 + quad * 8);

        // ================= strip A (rows i0..i0+15) =================
        {
            f32x4 s0 = __builtin_amdgcn_mfma_f32_16x16x32_bf16(qfA, k0, zero, 0, 0, 0);
            f32x4 s1 = __builtin_amdgcn_mfma_f32_16x16x32_bf16(qfA, k1, zero, 0, 0, 0);
            f32x4 s2 = __builtin_amdgcn_mfma_f32_16x16x32_bf16(qfA, k2, zero, 0, 0, 0);
            f32x4 s3 = __builtin_amdgcn_mfma_f32_16x16x32_bf16(qfA, k3, zero, 0, 0, 0);
            f32x4 q0 = __builtin_amdgcn_mfma_f32_16x16x32_bf16(qfA, e0, zero, 0, 0, 0);
            f32x4 q1 = __builtin_amdgcn_mfma_f32_16x16x32_bf16(qfA, e1, zero, 0, 0, 0);
            f32x4 q2 = __builtin_amdgcn_mfma_f32_16x16x32_bf16(qfA, e2, zero, 0, 0, 0);
            f32x4 q3 = __builtin_amdgcn_mfma_f32_16x16x32_bf16(qfA, e3, zero, 0, 0, 0);
            f32x4 q4 = __builtin_amdgcn_mfma_f32_16x16x32_bf16(qfA, e4, zero, 0, 0, 0);
            float p0[4], p1[4], p2[4], p3[4];
            #pragma unroll
            for (int r = 0; r < 4; ++r) {
                float f0 = bperm_f(addr4[r], q0[r]);
                float f1 = bperm_f(addr4[r], q1[r]);
                float f2 = bperm_f(addr4[r], q2[r]);
                float f3 = bperm_f(addr4[r], q3[r]);
                float f4 = bperm_f(addr4[r], q4[r]);
                p0[r] = EXP2F(s0[r] + (cond[r] ? f0 : f1));
                p1[r] = EXP2F(s1[r] + (cond[r] ? f1 : f2));
                p2[r] = EXP2F(s2[r] + (cond[r] ? f2 : f3));
                p3[r] = EXP2F(s3[r] + (cond[r] ? f3 : f4));
                lsumA[r] += (p0[r] + p1[r]) + (p2[r] + p3[r]);
            }
            #pragma unroll
            for (int r = 0; r < 4; ++r) {
                pbA0[pbw + 20 * r] = pack_bf16(p0[r], p1[r]);
                pbA1[pbw + 20 * r] = pack_bf16(p2[r], p3[r]);
            }
            bf16x8 pf0 = *reinterpret_cast<const bf16x8*>(&pbA0[pbr]);
            bf16x8 pf1 = *reinterpret_cast<const bf16x8*>(&pbA1[pbr]);
            oA0 = __builtin_amdgcn_mfma_f32_16x16x32_bf16(pf0, v0, oA0, 0, 0, 0);
            oA1 = __builtin_amdgcn_mfma_f32_16x16x32_bf16(pf0, v1, oA1, 0, 0, 0);
            oA0 = __builtin_amdgcn_mfma_f32_16x16x32_bf16(pf1, v2, oA0, 0, 0, 0);
            oA1 = __builtin_amdgcn_mfma_f32_16x16x32_bf16(pf1, v3, oA1, 0, 0, 0);
        }

        // ================= strip B (rows i0+16..i0+31) ==============
        // strip B's band block n == strip A's block n-1: uses em,e0..e3.
        {
            f32x4 s0 = __builtin_amdgcn_mfma_f32_16x16x32_bf16(qfB, k0, zero, 0, 0, 0);
            f32x4 s1 = __builtin_amdgcn_mfma_f32_16x16x32_bf16(qfB, k1, zero, 0, 0, 0);
            f32x4 s2 = __builtin_amdgcn_mfma_f32_16x16x32_bf16(qfB, k2, zero, 0, 0, 0);
            f32x4 s3 = __builtin_amdgcn_mfma_f32_16x16x32_bf16(qfB, k3, zero, 0, 0, 0);
            f32x4 q0 = __builtin_amdgcn_mfma_f32_16x16x32_bf16(qfB, em, zero, 0, 0, 0);
            f32x4 q1 = __builtin_amdgcn_mfma_f32_16x16x32_bf16(qfB, e0, zero, 0, 0, 0);
            f32x4 q2 = __builtin_amdgcn_mfma_f32_16x16x32_bf16(qfB, e1, zero, 0, 0, 0);
            f32x4 q3 = __builtin_amdgcn_mfma_f32_16x16x32_bf16(qfB, e2, zero, 0, 0, 0);
            f32x4 q4 = __builtin_amdgcn_mfma_f32_16x16x32_bf16(qfB, e3, zero, 0, 0, 0);
            float p0[4], p1[4], p2[4], p3[4];
            #pragma unroll
            for (int r = 0; r < 4; ++r) {
                float f0 = bperm_f(addr4[r], q0[r]);
                float f1 = bperm_f(addr4[r], q1[r]);
                float f2 = bperm_f(addr4[r], q2[r]);
                float f3 = bperm_f(addr4[r], q3[r]);
                float f4 = bperm_f(addr4[r], q4[r]);
                p0[r] = EXP2F(s0[r] + (cond[r] ? f0 : f1));
                p1[r] = EXP2F(s1[r] + (cond[r] ? f1 : f2));
                p2[r] = EXP2F(s2[r] + (cond[r] ? f2 : f3));
                p3[r] = EXP2F(s3[r] + (cond[r] ? f3 : f4));
                lsumB[r] += (p0[r] + p1[r]) + (p2[r] + p3[r]);
            }
            #pragma unroll
            for (int r = 0; r < 4; ++r) {
                pbB0[pbw + 20 * r] = pack_bf16(p0[r], p1[r]);
                pbB1[pbw + 20 * r] = pack_bf16(p2[r], p3[r]);
            }
            bf16x8 pf0 = *reinterpret_cast<const bf16x8*>(&pbB0[pbr]);
            bf16x8 pf1 = *reinterpret_cast<const bf16x8*>(&pbB1[pbr]);
            oB0 = __builtin_amdgcn_mfma_f32_16x16x32_bf16(pf0, v0, oB0, 0, 0, 0);
            oB1 = __builtin_amdgcn_mfma_f32_16x16x32_bf16(pf0, v1, oB1, 0, 0, 0);
            oB0 = __builtin_amdgcn_mfma_f32_16x16x32_bf16(pf1, v2, oB0, 0, 0, 0);
            oB1 = __builtin_amdgcn_mfma_f32_16x16x32_bf16(pf1, v3, oB1, 0, 0, 0);
        }
    }

    // reduce row sums across the 16 lanes of each quad-group; store
    #pragma unroll
    for (int r = 0; r < 4; ++r) {
        float va = lsumA[r], vb = lsumB[r];
        va += __shfl_xor(va, 1, 64);  vb += __shfl_xor(vb, 1, 64);
        va += __shfl_xor(va, 2, 64);  vb += __shfl_xor(vb, 2, 64);
        va += __shfl_xor(va, 4, 64);  vb += __shfl_xor(vb, 4, 64);
        va += __shfl_xor(va, 8, 64);  vb += __shfl_xor(vb, 8, 64);
        lsumA[r] = 1.0f / va;
        lsumB[r] = 1.0f / vb;
    }
    #pragma unroll
    for (int r = 0; r < 4; ++r) {
        const int srowA = i0 + quad * 4 + r;
        float* opA = out + ((size_t)b * Ss + srowA) * Ee + h * Dd;
        opA[li]      = oA0[r] * lsumA[r];
        opA[16 + li] = oA1[r] * lsumA[r];
        float* opB = opA + 16 * Ee;          // srowA + 16
        opB[li]      = oB0[r] * lsumB[r];
        opB[16 + li] = oB1[r] * lsumB[r];
    }
}

extern "C" void kernel_launch(void* const* d_in, const int* in_sizes, int n_in,
                              void* d_out, int out_size, void* d_ws, size_t ws_size,
                              hipStream_t stream) {
    const float* x  = (const float*)d_in[0];
    const float* Wq = (const float*)d_in[1];
    const float* Wk = (const float*)d_in[2];
    const float* Wv = (const float*)d_in[3];
    const float* Er = (const float*)d_in[4];
    float* out = (float*)d_out;

    // ws layout (bf16 elements; all offsets 16B-aligned)
    __hip_bfloat16* xb  = reinterpret_cast<__hip_bfloat16*>(d_ws);
    __hip_bfloat16* wbb = xb  + (size_t)8192 * 512;
    __hip_bfloat16* erb = wbb + (size_t)1536 * 512;
    __hip_bfloat16* Qs  = erb + 65536;                  // row 2047 = pad
    __hip_bfloat16* Kh  = Qs  + (size_t)Bb * Hh * Ss * Dd;
    __hip_bfloat16* Vt  = Kh  + (size_t)Bb * Hh * Ss * Dd;

    convert_kernel<<<4929, 256, 0, stream>>>(x, Wq, Wk, Wv, Er, xb, wbb, erb);
    proj_kernel<<<dim3(6, 128), 256, 0, stream>>>(
        xb, wbb, Qs, Kh, reinterpret_cast<unsigned*>(Vt));
    attn_kernel<<<dim3(1024), 256, 0, stream>>>(Qs, Kh, Vt, erb, out);
}